// Round 4
// baseline (317.793 us; speedup 1.0000x reference)
//
#include <hip/hip_runtime.h>
#include <cstdint>
#include <cstddef>

// B=2, S=512, D_MODEL=512, H=8, dk=64, N_SAMPLES=16; R = B*H*S = 8192 rows.
// JAX partitionable threefry: bits[i] = o0^o1, (o0,o1)=threefry2x32((0,42),(0,i))
// u = (float)(bits>>9) * 2^-23 ; select iff u < p ⟺ bits < (ceil(p*2^23))<<9

#if __has_builtin(__builtin_amdgcn_alignbit)
#define ROTL(x, r) __builtin_amdgcn_alignbit((x), (x), 32 - (r))
#else
#define ROTL(x, r) (((x) << (r)) | ((x) >> (32 - (r))))
#endif

// 4-wide interleaved threefry2x32, key (0,42): inputs are counters PRE-OFFSET
// by ks[1]=42; returns folded o0^o1 per chain. 4 independent dep-chains give
// the SIMD issue slots something to do during the 4-cyc VALU dep latency.
__device__ __forceinline__ void tf4_fold(uint32_t ca, uint32_t cb, uint32_t cc,
                                         uint32_t cd, uint32_t &ra,
                                         uint32_t &rb, uint32_t &rc,
                                         uint32_t &rd) {
  uint32_t a0 = 0u, a1 = ca, b0 = 0u, b1 = cb;
  uint32_t c0 = 0u, c1 = cc, d0 = 0u, d1 = cd;
#define QR(s)                                                                 \
  a0 += a1; b0 += b1; c0 += c1; d0 += d1;                                     \
  a1 = ROTL(a1, s); b1 = ROTL(b1, s); c1 = ROTL(c1, s); d1 = ROTL(d1, s);     \
  a1 ^= a0; b1 ^= b0; c1 ^= c0; d1 ^= d0;
#define INJ(x, y)                                                             \
  a0 += (x); b0 += (x); c0 += (x); d0 += (x);                                 \
  a1 += (y); b1 += (y); c1 += (y); d1 += (y);
  QR(13) QR(15) QR(26) QR(6)
  INJ(42u, 0x1BD11BF1u)
  QR(17) QR(29) QR(16) QR(24)
  INJ(0x1BD11BF0u, 2u)
  QR(13) QR(15) QR(26) QR(6)
  a1 += 45u; b1 += 45u; c1 += 45u; d1 += 45u;   // x0 += ks[0]=0
  QR(17) QR(29) QR(16) QR(24)
  INJ(42u, 0x1BD11BF4u)
  QR(13) QR(15) QR(26) QR(6)
  INJ(0x1BD11BF0u, 5u)
#undef QR
#undef INJ
  ra = a0 ^ a1; rb = b0 ^ b1; rc = c0 ^ c1; rd = d0 ^ d1;
}

// ---------------------------------------------------------------------------
// Kernel A: QKV projection. grid=(16,8,3), block=256. 64x64 tile, BK=32,
// 4x4 per thread, float4 LDS fragments both sides. k-order == prior rounds.
// ---------------------------------------------------------------------------
__global__ __launch_bounds__(256)
void qkv_gemm(const float* __restrict__ x,
              const float* __restrict__ Wq, const float* __restrict__ bq,
              const float* __restrict__ Wk, const float* __restrict__ bk,
              const float* __restrict__ Wv, const float* __restrict__ bv,
              float* __restrict__ Qw, float* __restrict__ Kw,
              float* __restrict__ Vw) {
  const float* W; const float* bias; float* out;
  if (blockIdx.z == 0)      { W = Wq; bias = bq; out = Qw; }
  else if (blockIdx.z == 1) { W = Wk; bias = bk; out = Kw; }
  else                      { W = Wv; bias = bv; out = Vw; }

  __shared__ float At[32][68];   // [k][m], stride 68 => float4-aligned rows
  __shared__ float Bs[32][64];   // [k][n]
  const int tid = threadIdx.x;
  const int tx = tid & 15, ty = tid >> 4;
  const int row0 = blockIdx.x * 64, col0 = blockIdx.y * 64;
  float acc[4][4] = {};

  for (int kk = 0; kk < 512; kk += 32) {
    const int ar = tid >> 2;
#pragma unroll
    for (int i = 0; i < 2; ++i) {
      const int kc = ((tid & 3) << 3) + (i << 2);
      const float4 a4 =
          *(const float4*)&x[(size_t)(row0 + ar) * 512 + kk + kc];
      At[kc + 0][ar] = a4.x; At[kc + 1][ar] = a4.y;
      At[kc + 2][ar] = a4.z; At[kc + 3][ar] = a4.w;
    }
#pragma unroll
    for (int i = 0; i < 2; ++i) {
      const int idx = tid + (i << 8);
      const int br = idx >> 4, bc = (idx & 15) << 2;
      *(float4*)&Bs[br][bc] =
          *(const float4*)&W[(size_t)(kk + br) * 512 + col0 + bc];
    }
    __syncthreads();
#pragma unroll
    for (int p = 0; p < 32; ++p) {
      const float4 a4 = *(const float4*)&At[p][ty << 2];
      const float4 b4 = *(const float4*)&Bs[p][tx << 2];
      acc[0][0] = fmaf(a4.x, b4.x, acc[0][0]); acc[0][1] = fmaf(a4.x, b4.y, acc[0][1]);
      acc[0][2] = fmaf(a4.x, b4.z, acc[0][2]); acc[0][3] = fmaf(a4.x, b4.w, acc[0][3]);
      acc[1][0] = fmaf(a4.y, b4.x, acc[1][0]); acc[1][1] = fmaf(a4.y, b4.y, acc[1][1]);
      acc[1][2] = fmaf(a4.y, b4.z, acc[1][2]); acc[1][3] = fmaf(a4.y, b4.w, acc[1][3]);
      acc[2][0] = fmaf(a4.z, b4.x, acc[2][0]); acc[2][1] = fmaf(a4.z, b4.y, acc[2][1]);
      acc[2][2] = fmaf(a4.z, b4.z, acc[2][2]); acc[2][3] = fmaf(a4.z, b4.w, acc[2][3]);
      acc[3][0] = fmaf(a4.w, b4.x, acc[3][0]); acc[3][1] = fmaf(a4.w, b4.y, acc[3][1]);
      acc[3][2] = fmaf(a4.w, b4.z, acc[3][2]); acc[3][3] = fmaf(a4.w, b4.w, acc[3][3]);
    }
    __syncthreads();
  }
#pragma unroll
  for (int i = 0; i < 4; ++i) {
    const int row = row0 + (ty << 2) + i;
    const int b = row >> 9, s = row & 511;
#pragma unroll
    for (int j = 0; j < 4; ++j) {
      const int col = col0 + (tx << 2) + j;
      const int h = col >> 6, d = col & 63;
      out[(((size_t)(b * 8 + h) * 512 + s) * 64) + d] = acc[i][j] + bias[col];
    }
  }
}

// ---------------------------------------------------------------------------
// Kernel C: output projection. grid=(16,8). Same 64x64 structure.
// ---------------------------------------------------------------------------
__global__ __launch_bounds__(256)
void out_gemm(const float* __restrict__ A, const float* __restrict__ W,
              const float* __restrict__ bias, float* __restrict__ C) {
  __shared__ float At[32][68];
  __shared__ float Bs[32][64];
  const int tid = threadIdx.x;
  const int tx = tid & 15, ty = tid >> 4;
  const int row0 = blockIdx.x * 64, col0 = blockIdx.y * 64;
  float acc[4][4] = {};

  for (int kk = 0; kk < 512; kk += 32) {
    const int ar = tid >> 2;
#pragma unroll
    for (int i = 0; i < 2; ++i) {
      const int kc = ((tid & 3) << 3) + (i << 2);
      const float4 a4 =
          *(const float4*)&A[(size_t)(row0 + ar) * 512 + kk + kc];
      At[kc + 0][ar] = a4.x; At[kc + 1][ar] = a4.y;
      At[kc + 2][ar] = a4.z; At[kc + 3][ar] = a4.w;
    }
#pragma unroll
    for (int i = 0; i < 2; ++i) {
      const int idx = tid + (i << 8);
      const int br = idx >> 4, bc = (idx & 15) << 2;
      *(float4*)&Bs[br][bc] =
          *(const float4*)&W[(size_t)(kk + br) * 512 + col0 + bc];
    }
    __syncthreads();
#pragma unroll
    for (int p = 0; p < 32; ++p) {
      const float4 a4 = *(const float4*)&At[p][ty << 2];
      const float4 b4 = *(const float4*)&Bs[p][tx << 2];
      acc[0][0] = fmaf(a4.x, b4.x, acc[0][0]); acc[0][1] = fmaf(a4.x, b4.y, acc[0][1]);
      acc[0][2] = fmaf(a4.x, b4.z, acc[0][2]); acc[0][3] = fmaf(a4.x, b4.w, acc[0][3]);
      acc[1][0] = fmaf(a4.y, b4.x, acc[1][0]); acc[1][1] = fmaf(a4.y, b4.y, acc[1][1]);
      acc[1][2] = fmaf(a4.y, b4.z, acc[1][2]); acc[1][3] = fmaf(a4.y, b4.w, acc[1][3]);
      acc[2][0] = fmaf(a4.z, b4.x, acc[2][0]); acc[2][1] = fmaf(a4.z, b4.y, acc[2][1]);
      acc[2][2] = fmaf(a4.z, b4.z, acc[2][2]); acc[2][3] = fmaf(a4.z, b4.w, acc[2][3]);
      acc[3][0] = fmaf(a4.w, b4.x, acc[3][0]); acc[3][1] = fmaf(a4.w, b4.y, acc[3][1]);
      acc[3][2] = fmaf(a4.w, b4.z, acc[3][2]); acc[3][3] = fmaf(a4.w, b4.w, acc[3][3]);
    }
    __syncthreads();
  }
#pragma unroll
  for (int i = 0; i < 4; ++i) {
    const int row = row0 + (ty << 2) + i;
#pragma unroll
    for (int j = 0; j < 4; ++j) {
      const int col = col0 + (tx << 2) + j;
      C[(size_t)row * 512 + col] = acc[i][j] + bias[col];
    }
  }
}

// ---------------------------------------------------------------------------
// Kernel B (FUSED): scores + softmax + sampling + sparse attn@V.
// One block per row r (8192). tf never leaves LDS. Dot/softmax sequence is
// bit-identical to the prior passing round -> identical sampling decisions.
// ---------------------------------------------------------------------------
__global__ __launch_bounds__(256)
void fused_sample(const float* __restrict__ Q, const float* __restrict__ Kt,
                  const float* __restrict__ V, float* __restrict__ ao) {
  const int r = blockIdx.x;                   // 0..8191
  const int bh = r >> 9, q = r & 511;
  const int b = r >> 12, h = (r >> 9) & 7;
  const int tid = threadIdx.x;
  __shared__ __align__(16) float qs[64];
  __shared__ float red[8];
  __shared__ float tf[512];
  __shared__ uint32_t pscu[512];              // ceil(p*2^23)<<9
  __shared__ float wa[512];
  __shared__ float wr[16];
  __shared__ float redc[8];
  __shared__ float psum[4][64];
  __shared__ int   list[512];
  __shared__ int   cnt;

  if (tid == 0) cnt = 0;
  if (tid < 64) qs[tid] = Q[((size_t)bh * 512 + q) * 64 + tid];
  __syncthreads();

  // ---- scores: k = tid, tid+256 (same fma order as prior round) ----
  float sc[2];
#pragma unroll
  for (int ii = 0; ii < 2; ++ii) {
    const int k = tid + (ii << 8);
    const float4* Kp = (const float4*)(Kt + ((size_t)bh * 512 + k) * 64);
    const float4* Qp = (const float4*)qs;
    float s = 0.f;
#pragma unroll
    for (int d4 = 0; d4 < 16; ++d4) {
      const float4 kv = Kp[d4], qv = Qp[d4];
      s = fmaf(qv.x, kv.x, s); s = fmaf(qv.y, kv.y, s);
      s = fmaf(qv.z, kv.z, s); s = fmaf(qv.w, kv.w, s);
    }
    sc[ii] = s * 0.125f;
  }
  // ---- softmax ----
  float mx = fmaxf(sc[0], sc[1]);
  for (int m = 1; m < 64; m <<= 1) mx = fmaxf(mx, __shfl_xor(mx, m));
  if ((tid & 63) == 0) red[tid >> 6] = mx;
  __syncthreads();
  const float rowmax = fmaxf(fmaxf(red[0], red[1]), fmaxf(red[2], red[3]));
  const float e0 = expf(sc[0] - rowmax);
  const float e1 = expf(sc[1] - rowmax);
  float ssum = e0 + e1;
  for (int m = 1; m < 64; m <<= 1) ssum += __shfl_xor(ssum, m);
  if ((tid & 63) == 0) red[4 + (tid >> 6)] = ssum;
  __syncthreads();
  const float tot = red[4] + red[5] + red[6] + red[7];
  const float t0 = e0 / tot, t1 = e1 / tot;
  tf[tid] = t0; tf[tid + 256] = t1;
  wa[tid] = 0.f; wa[tid + 256] = 0.f;
  {
    const float p0 = fmaf(0.5f, t0, 0.0009765625f);
    const float p1 = fmaf(0.5f, t1, 0.0009765625f);
    pscu[tid]       = ((uint32_t)ceilf(p0 * 8388608.0f)) << 9;
    pscu[tid + 256] = ((uint32_t)ceilf(p1 * 8388608.0f)) << 9;
    float ql = (1.f - p0) * (1.f - p1);       // Qrow partial
    for (int m = 1; m < 64; m <<= 1) ql *= __shfl_xor(ql, m);
    if ((tid & 63) == 0) redc[4 + (tid >> 6)] = ql;
  }
  __syncthreads();
  const float Qrow = redc[4] * redc[5] * redc[6] * redc[7];

  // ---- sampling: 16 samples x 16 lanes; lane covers k = t + 16j ----
  const int n = tid >> 4, t = tid & 15;
  const uint32_t cnt42 =
      (uint32_t)r * 8192u + (uint32_t)n * 512u + (uint32_t)t + 42u;
  uint32_t bits = 0u;
  for (int j = 0; j < 32; j += 4) {
    uint32_t ra, rb, rc, rd;
    tf4_fold(cnt42 + (uint32_t)(j << 4), cnt42 + (uint32_t)((j + 1) << 4),
             cnt42 + (uint32_t)((j + 2) << 4), cnt42 + (uint32_t)((j + 3) << 4),
             ra, rb, rc, rd);
    const uint32_t pa = pscu[t + (j << 4)];
    const uint32_t pb = pscu[t + ((j + 1) << 4)];
    const uint32_t pc = pscu[t + ((j + 2) << 4)];
    const uint32_t pd = pscu[t + ((j + 3) << 4)];
    bits |= (ra < pa ? 1u : 0u) << j;
    bits |= (rb < pb ? 1u : 0u) << (j + 1);
    bits |= (rc < pc ? 1u : 0u) << (j + 2);
    bits |= (rd < pd ? 1u : 0u) << (j + 3);
  }

  // rare path: selected-term products
  float ptl = 1.f, ratl = 1.f;
  int cl = __popc(bits);
  {
    uint32_t bb = bits;
    while (bb) {
      const int j = __builtin_ctz(bb);
      bb &= bb - 1u;
      const float tv = tf[t + (j << 4)];
      const float p = fmaf(0.5f, tv, 0.0009765625f);
      ptl *= tv;
      ratl *= p / (1.f - p);
    }
  }
#pragma unroll
  for (int m = 1; m < 16; m <<= 1) {
    ptl *= __shfl_xor(ptl, m);
    ratl *= __shfl_xor(ratl, m);
    cl += __shfl_xor(cl, m);
  }
  if (t == 0) {
    const float pp = Qrow * ratl;
    wr[n] = (cl > 0 && pp > 0.f) ? (ptl / fmaxf(pp, 1e-38f)) : 0.f;
  }
  __syncthreads();
  float wsum = 0.f;
#pragma unroll
  for (int m2 = 0; m2 < 16; ++m2) wsum += wr[m2];
  const float wn = (wsum > 0.f) ? (wr[n] / fmaxf(wsum, 1e-38f)) : 0.0625f;
  {
    uint32_t bb = bits;
    while (bb) {
      const int j = __builtin_ctz(bb);
      bb &= bb - 1u;
      atomicAdd(&wa[t + (j << 4)], wn);
    }
  }
  __syncthreads();

  // row sum + compact nonzeros
  float sp = wa[tid] + wa[tid + 256];
  for (int m = 1; m < 64; m <<= 1) sp += __shfl_xor(sp, m);
  if ((tid & 63) == 0) redc[tid >> 6] = sp;
  if (wa[tid] > 0.f)       { const int i = atomicAdd(&cnt, 1); list[i] = tid; }
  if (wa[tid + 256] > 0.f) { const int i = atomicAdd(&cnt, 1); list[i] = tid + 256; }
  __syncthreads();
  const float was = redc[0] + redc[1] + redc[2] + redc[3];
  const int nnz = cnt;

  // sparse attn @ V over ~16 nonzero k
  const int g = tid >> 6, d = tid & 63;
  const float* Vb = V + ((size_t)(b * 8 + h) * 512) * 64;
  float acc = 0.f;
  if (was > 0.f) {
    const float inv = 1.f / fmaxf(was, 1e-38f);
    for (int i = g; i < nnz; i += 4) {
      const int k = list[i];
      acc = fmaf(wa[k] * inv, Vb[(size_t)k * 64 + d], acc);
    }
  } else {
    for (int k = g; k < 512; k += 4) acc += Vb[(size_t)k * 64 + d];
    acc *= 0.001953125f;
  }
  psum[g][d] = acc;
  __syncthreads();
  if (g == 0) {
    ao[((size_t)(b * 512 + q) * 512) + h * 64 + d] =
        psum[0][d] + psum[1][d] + psum[2][d] + psum[3][d];
  }
}

// ---------------------------------------------------------------------------
extern "C" void kernel_launch(void* const* d_in, const int* in_sizes, int n_in,
                              void* d_out, int out_size, void* d_ws,
                              size_t ws_size, hipStream_t stream) {
  const float* x  = (const float*)d_in[0];
  const float* Wq = (const float*)d_in[1];
  const float* bq = (const float*)d_in[2];
  const float* Wk = (const float*)d_in[3];
  const float* bk = (const float*)d_in[4];
  const float* Wv = (const float*)d_in[5];
  const float* bv = (const float*)d_in[6];
  const float* Wo = (const float*)d_in[7];
  const float* bo = (const float*)d_in[8];
  float* out = (float*)d_out;

  float* ws = (float*)d_ws;
  float* Qw = ws;                  // 524288 f32  [B,H,S,dk]
  float* Kw = ws + 524288;         // 524288
  float* Vw = ws + 1048576;        // 524288
  float* ao = ws + 1572864;        // 524288     [B,S,D]

  dim3 gq(16, 8, 3);
  qkv_gemm<<<gq, 256, 0, stream>>>(x, Wq, bq, Wk, bk, Wv, bv, Qw, Kw, Vw);
  fused_sample<<<8192, 256, 0, stream>>>(Qw, Kw, Vw, ao);
  dim3 go(16, 8);
  out_gemm<<<go, 256, 0, stream>>>(ao, Wo, bo, out);
}

// Round 6
// 307.862 us; speedup vs baseline: 1.0323x; 1.0323x over previous
//
#include <hip/hip_runtime.h>
#include <cstdint>
#include <cstddef>

// B=2, S=512, D_MODEL=512, H=8, dk=64, N_SAMPLES=16; R = B*H*S = 8192 rows.
// JAX partitionable threefry: bits[i] = o0^o1, (o0,o1)=threefry2x32((0,42),(0,i))
// u = (float)(bits>>9) * 2^-23 ; select iff u < p ⟺ bits < (ceil(p*2^23))<<9

#if __has_builtin(__builtin_amdgcn_alignbit)
#define ROTL(x, r) __builtin_amdgcn_alignbit((x), (x), 32 - (r))
#else
#define ROTL(x, r) (((x) << (r)) | ((x) >> (32 - (r))))
#endif

// 4-wide interleaved threefry2x32, key (0,42): inputs are counters PRE-OFFSET
// by ks[1]=42; returns folded o0^o1 per chain. 4 independent dep-chains fill
// the 4-cyc VALU dep-latency window within a single wave.
__device__ __forceinline__ void tf4_fold(uint32_t ca, uint32_t cb, uint32_t cc,
                                         uint32_t cd, uint32_t &ra,
                                         uint32_t &rb, uint32_t &rc,
                                         uint32_t &rd) {
  uint32_t a0 = 0u, a1 = ca, b0 = 0u, b1 = cb;
  uint32_t c0 = 0u, c1 = cc, d0 = 0u, d1 = cd;
#define QR(s)                                                                 \
  a0 += a1; b0 += b1; c0 += c1; d0 += d1;                                     \
  a1 = ROTL(a1, s); b1 = ROTL(b1, s); c1 = ROTL(c1, s); d1 = ROTL(d1, s);     \
  a1 ^= a0; b1 ^= b0; c1 ^= c0; d1 ^= d0;
#define INJ(x, y)                                                             \
  a0 += (x); b0 += (x); c0 += (x); d0 += (x);                                 \
  a1 += (y); b1 += (y); c1 += (y); d1 += (y);
  QR(13) QR(15) QR(26) QR(6)
  INJ(42u, 0x1BD11BF1u)
  QR(17) QR(29) QR(16) QR(24)
  INJ(0x1BD11BF0u, 2u)
  QR(13) QR(15) QR(26) QR(6)
  a1 += 45u; b1 += 45u; c1 += 45u; d1 += 45u;   // x0 += ks[0]=0
  QR(17) QR(29) QR(16) QR(24)
  INJ(42u, 0x1BD11BF4u)
  QR(13) QR(15) QR(26) QR(6)
  INJ(0x1BD11BF0u, 5u)
#undef QR
#undef INJ
  ra = a0 ^ a1; rb = b0 ^ b1; rc = c0 ^ c1; rd = d0 ^ d1;
}

// ---------------------------------------------------------------------------
// Kernel A: QKV projection. grid=(16,8,3), block=256. 64x64 tile, BK=32,
// 4x4 per thread, float4 LDS fragments both sides. k-order == prior rounds.
// ---------------------------------------------------------------------------
__global__ __launch_bounds__(256)
void qkv_gemm(const float* __restrict__ x,
              const float* __restrict__ Wq, const float* __restrict__ bq,
              const float* __restrict__ Wk, const float* __restrict__ bk,
              const float* __restrict__ Wv, const float* __restrict__ bv,
              float* __restrict__ Qw, float* __restrict__ Kw,
              float* __restrict__ Vw) {
  const float* W; const float* bias; float* out;
  if (blockIdx.z == 0)      { W = Wq; bias = bq; out = Qw; }
  else if (blockIdx.z == 1) { W = Wk; bias = bk; out = Kw; }
  else                      { W = Wv; bias = bv; out = Vw; }

  __shared__ float At[32][68];   // [k][m], stride 68 => float4-aligned rows
  __shared__ float Bs[32][64];   // [k][n]
  const int tid = threadIdx.x;
  const int tx = tid & 15, ty = tid >> 4;
  const int row0 = blockIdx.x * 64, col0 = blockIdx.y * 64;
  float acc[4][4] = {};

  for (int kk = 0; kk < 512; kk += 32) {
    const int ar = tid >> 2;
#pragma unroll
    for (int i = 0; i < 2; ++i) {
      const int kc = ((tid & 3) << 3) + (i << 2);
      const float4 a4 =
          *(const float4*)&x[(size_t)(row0 + ar) * 512 + kk + kc];
      At[kc + 0][ar] = a4.x; At[kc + 1][ar] = a4.y;
      At[kc + 2][ar] = a4.z; At[kc + 3][ar] = a4.w;
    }
#pragma unroll
    for (int i = 0; i < 2; ++i) {
      const int idx = tid + (i << 8);
      const int br = idx >> 4, bc = (idx & 15) << 2;
      *(float4*)&Bs[br][bc] =
          *(const float4*)&W[(size_t)(kk + br) * 512 + col0 + bc];
    }
    __syncthreads();
#pragma unroll
    for (int p = 0; p < 32; ++p) {
      const float4 a4 = *(const float4*)&At[p][ty << 2];
      const float4 b4 = *(const float4*)&Bs[p][tx << 2];
      acc[0][0] = fmaf(a4.x, b4.x, acc[0][0]); acc[0][1] = fmaf(a4.x, b4.y, acc[0][1]);
      acc[0][2] = fmaf(a4.x, b4.z, acc[0][2]); acc[0][3] = fmaf(a4.x, b4.w, acc[0][3]);
      acc[1][0] = fmaf(a4.y, b4.x, acc[1][0]); acc[1][1] = fmaf(a4.y, b4.y, acc[1][1]);
      acc[1][2] = fmaf(a4.y, b4.z, acc[1][2]); acc[1][3] = fmaf(a4.y, b4.w, acc[1][3]);
      acc[2][0] = fmaf(a4.z, b4.x, acc[2][0]); acc[2][1] = fmaf(a4.z, b4.y, acc[2][1]);
      acc[2][2] = fmaf(a4.z, b4.z, acc[2][2]); acc[2][3] = fmaf(a4.z, b4.w, acc[2][3]);
      acc[3][0] = fmaf(a4.w, b4.x, acc[3][0]); acc[3][1] = fmaf(a4.w, b4.y, acc[3][1]);
      acc[3][2] = fmaf(a4.w, b4.z, acc[3][2]); acc[3][3] = fmaf(a4.w, b4.w, acc[3][3]);
    }
    __syncthreads();
  }
#pragma unroll
  for (int i = 0; i < 4; ++i) {
    const int row = row0 + (ty << 2) + i;
    const int b = row >> 9, s = row & 511;
#pragma unroll
    for (int j = 0; j < 4; ++j) {
      const int col = col0 + (tx << 2) + j;
      const int h = col >> 6, d = col & 63;
      out[(((size_t)(b * 8 + h) * 512 + s) * 64) + d] = acc[i][j] + bias[col];
    }
  }
}

// ---------------------------------------------------------------------------
// Kernel D: output projection. grid=(16,8). Same 64x64 structure.
// ---------------------------------------------------------------------------
__global__ __launch_bounds__(256)
void out_gemm(const float* __restrict__ A, const float* __restrict__ W,
              const float* __restrict__ bias, float* __restrict__ C) {
  __shared__ float At[32][68];
  __shared__ float Bs[32][64];
  const int tid = threadIdx.x;
  const int tx = tid & 15, ty = tid >> 4;
  const int row0 = blockIdx.x * 64, col0 = blockIdx.y * 64;
  float acc[4][4] = {};

  for (int kk = 0; kk < 512; kk += 32) {
    const int ar = tid >> 2;
#pragma unroll
    for (int i = 0; i < 2; ++i) {
      const int kc = ((tid & 3) << 3) + (i << 2);
      const float4 a4 =
          *(const float4*)&A[(size_t)(row0 + ar) * 512 + kk + kc];
      At[kc + 0][ar] = a4.x; At[kc + 1][ar] = a4.y;
      At[kc + 2][ar] = a4.z; At[kc + 3][ar] = a4.w;
    }
#pragma unroll
    for (int i = 0; i < 2; ++i) {
      const int idx = tid + (i << 8);
      const int br = idx >> 4, bc = (idx & 15) << 2;
      *(float4*)&Bs[br][bc] =
          *(const float4*)&W[(size_t)(kk + br) * 512 + col0 + bc];
    }
    __syncthreads();
#pragma unroll
    for (int p = 0; p < 32; ++p) {
      const float4 a4 = *(const float4*)&At[p][ty << 2];
      const float4 b4 = *(const float4*)&Bs[p][tx << 2];
      acc[0][0] = fmaf(a4.x, b4.x, acc[0][0]); acc[0][1] = fmaf(a4.x, b4.y, acc[0][1]);
      acc[0][2] = fmaf(a4.x, b4.z, acc[0][2]); acc[0][3] = fmaf(a4.x, b4.w, acc[0][3]);
      acc[1][0] = fmaf(a4.y, b4.x, acc[1][0]); acc[1][1] = fmaf(a4.y, b4.y, acc[1][1]);
      acc[1][2] = fmaf(a4.y, b4.z, acc[1][2]); acc[1][3] = fmaf(a4.y, b4.w, acc[1][3]);
      acc[2][0] = fmaf(a4.z, b4.x, acc[2][0]); acc[2][1] = fmaf(a4.z, b4.y, acc[2][1]);
      acc[2][2] = fmaf(a4.z, b4.z, acc[2][2]); acc[2][3] = fmaf(a4.z, b4.w, acc[2][3]);
      acc[3][0] = fmaf(a4.w, b4.x, acc[3][0]); acc[3][1] = fmaf(a4.w, b4.y, acc[3][1]);
      acc[3][2] = fmaf(a4.w, b4.z, acc[3][2]); acc[3][3] = fmaf(a4.w, b4.w, acc[3][3]);
    }
    __syncthreads();
  }
#pragma unroll
  for (int i = 0; i < 4; ++i) {
    const int row = row0 + (ty << 2) + i;
#pragma unroll
    for (int j = 0; j < 4; ++j) {
      const int col = col0 + (tx << 2) + j;
      C[(size_t)row * 512 + col] = acc[i][j] + bias[col];
    }
  }
}

// ---------------------------------------------------------------------------
// Kernel B: scores + softmax -> tf. 4 q-rows per block (K-row reuse x4).
// grid = 2048: blk = bh*128 + qtile. Dot order identical to prior rounds.
// ---------------------------------------------------------------------------
__global__ __launch_bounds__(256)
void scores_softmax(const float* __restrict__ Q, const float* __restrict__ Kt,
                    float* __restrict__ tf_g) {
  const int blk = blockIdx.x;
  const int bh = blk >> 7, q0 = (blk & 127) << 2;
  const int tid = threadIdx.x;
  __shared__ __align__(16) float qs[4][64];
  __shared__ float redm[4][4], reds[4][4];
  qs[tid >> 6][tid & 63] =
      Q[((size_t)bh * 512 + q0 + (tid >> 6)) * 64 + (tid & 63)];
  __syncthreads();

  float sc[4][2];
#pragma unroll
  for (int ii = 0; ii < 2; ++ii) {
    const int k = tid + ii * 256;
    const float4* Kp = (const float4*)(Kt + ((size_t)bh * 512 + k) * 64);
    float a0 = 0.f, a1 = 0.f, a2 = 0.f, a3 = 0.f;
#pragma unroll
    for (int d4 = 0; d4 < 16; ++d4) {
      const float4 kv = Kp[d4];
      const float4 v0 = ((const float4*)qs[0])[d4];
      const float4 v1 = ((const float4*)qs[1])[d4];
      const float4 v2 = ((const float4*)qs[2])[d4];
      const float4 v3 = ((const float4*)qs[3])[d4];
      a0 = fmaf(v0.x, kv.x, a0); a0 = fmaf(v0.y, kv.y, a0);
      a0 = fmaf(v0.z, kv.z, a0); a0 = fmaf(v0.w, kv.w, a0);
      a1 = fmaf(v1.x, kv.x, a1); a1 = fmaf(v1.y, kv.y, a1);
      a1 = fmaf(v1.z, kv.z, a1); a1 = fmaf(v1.w, kv.w, a1);
      a2 = fmaf(v2.x, kv.x, a2); a2 = fmaf(v2.y, kv.y, a2);
      a2 = fmaf(v2.z, kv.z, a2); a2 = fmaf(v2.w, kv.w, a2);
      a3 = fmaf(v3.x, kv.x, a3); a3 = fmaf(v3.y, kv.y, a3);
      a3 = fmaf(v3.z, kv.z, a3); a3 = fmaf(v3.w, kv.w, a3);
    }
    sc[0][ii] = a0 * 0.125f; sc[1][ii] = a1 * 0.125f;
    sc[2][ii] = a2 * 0.125f; sc[3][ii] = a3 * 0.125f;
  }
  float mx[4];
#pragma unroll
  for (int i = 0; i < 4; ++i) mx[i] = fmaxf(sc[i][0], sc[i][1]);
  for (int m = 1; m < 64; m <<= 1) {
#pragma unroll
    for (int i = 0; i < 4; ++i) mx[i] = fmaxf(mx[i], __shfl_xor(mx[i], m));
  }
  if ((tid & 63) == 0) {
    const int w = tid >> 6;
#pragma unroll
    for (int i = 0; i < 4; ++i) redm[i][w] = mx[i];
  }
  __syncthreads();
  float ex[4][2], sm[4];
#pragma unroll
  for (int i = 0; i < 4; ++i) {
    const float rm = fmaxf(fmaxf(redm[i][0], redm[i][1]),
                           fmaxf(redm[i][2], redm[i][3]));
    ex[i][0] = expf(sc[i][0] - rm);
    ex[i][1] = expf(sc[i][1] - rm);
    sm[i] = ex[i][0] + ex[i][1];
  }
  for (int m = 1; m < 64; m <<= 1) {
#pragma unroll
    for (int i = 0; i < 4; ++i) sm[i] += __shfl_xor(sm[i], m);
  }
  if ((tid & 63) == 0) {
    const int w = tid >> 6;
#pragma unroll
    for (int i = 0; i < 4; ++i) reds[i][w] = sm[i];
  }
  __syncthreads();
#pragma unroll
  for (int i = 0; i < 4; ++i) {
    const float tot = reds[i][0] + reds[i][1] + reds[i][2] + reds[i][3];
    tf_g[((size_t)bh * 512 + q0 + i) * 512 + tid]       = ex[i][0] / tot;
    tf_g[((size_t)bh * 512 + q0 + i) * 512 + tid + 256] = ex[i][1] / tot;
  }
}

// ---------------------------------------------------------------------------
// Kernel C: sampling + sparse weighted attn@V.  One block per row r.
// 256 threads = 16 samples x 16 lanes; lane covers k = t + 16j, j<32.
// Hot loop: 4-wide threefry + register-resident thresholds, zero LDS/mem.
// ---------------------------------------------------------------------------
__global__ __launch_bounds__(256)
void sample_attnv(const float* __restrict__ tf_g, const float* __restrict__ V,
                  float* __restrict__ ao) {
  const int r = blockIdx.x;                   // 0..8191
  const int b = r >> 12, h = (r >> 9) & 7, q = r & 511;
  const int tid = threadIdx.x;
  __shared__ float tf[512];
  __shared__ uint32_t pscu[512];              // ceil(p*2^23)<<9
  __shared__ float wa[512];
  __shared__ float wr[16];
  __shared__ float redc[8];
  __shared__ float psum[4][64];
  __shared__ int   list[512];
  __shared__ int   cnt;

  if (tid == 0) cnt = 0;
  {
    const float t0 = tf_g[(size_t)r * 512 + tid];
    const float t1 = tf_g[(size_t)r * 512 + tid + 256];
    tf[tid] = t0; tf[tid + 256] = t1;
    wa[tid] = 0.f; wa[tid + 256] = 0.f;
    const float p0 = fmaf(0.5f, t0, 0.0009765625f);
    const float p1 = fmaf(0.5f, t1, 0.0009765625f);
    pscu[tid]       = ((uint32_t)ceilf(p0 * 8388608.0f)) << 9;
    pscu[tid + 256] = ((uint32_t)ceilf(p1 * 8388608.0f)) << 9;
    float ql = (1.f - p0) * (1.f - p1);       // Qrow partial
    for (int m = 1; m < 64; m <<= 1) ql *= __shfl_xor(ql, m);
    if ((tid & 63) == 0) redc[4 + (tid >> 6)] = ql;
  }
  __syncthreads();
  const float Qrow = redc[4] * redc[5] * redc[6] * redc[7];

  const int n = tid >> 4, t = tid & 15;
  // hoist all 32 thresholds into registers; hot loop is then pure VALU
  uint32_t pv[32];
#pragma unroll
  for (int j = 0; j < 32; ++j) pv[j] = pscu[t + (j << 4)];

  const uint32_t cnt42 =
      (uint32_t)r * 8192u + (uint32_t)n * 512u + (uint32_t)t + 42u;
  uint32_t bits = 0u;
#pragma unroll
  for (int j = 0; j < 32; j += 4) {
    uint32_t ra, rb, rc, rd;
    tf4_fold(cnt42 + (uint32_t)(j << 4), cnt42 + (uint32_t)((j + 1) << 4),
             cnt42 + (uint32_t)((j + 2) << 4), cnt42 + (uint32_t)((j + 3) << 4),
             ra, rb, rc, rd);
    bits |= (ra < pv[j] ? 1u : 0u) << j;
    bits |= (rb < pv[j + 1] ? 1u : 0u) << (j + 1);
    bits |= (rc < pv[j + 2] ? 1u : 0u) << (j + 2);
    bits |= (rd < pv[j + 3] ? 1u : 0u) << (j + 3);
  }

  // rare path: selected-term products (expected ~1 selection per sample)
  float ptl = 1.f, ratl = 1.f;
  int cl = __popc(bits);
  {
    uint32_t bb = bits;
    while (bb) {
      const int j = __builtin_ctz(bb);
      bb &= bb - 1u;
      const float tv = tf[t + (j << 4)];
      const float p = fmaf(0.5f, tv, 0.0009765625f);
      ptl *= tv;
      ratl *= p / (1.f - p);
    }
  }
#pragma unroll
  for (int m = 1; m < 16; m <<= 1) {
    ptl *= __shfl_xor(ptl, m);
    ratl *= __shfl_xor(ratl, m);
    cl += __shfl_xor(cl, m);
  }
  if (t == 0) {
    const float pp = Qrow * ratl;
    wr[n] = (cl > 0 && pp > 0.f) ? (ptl / fmaxf(pp, 1e-38f)) : 0.f;
  }
  __syncthreads();
  float wsum = 0.f;
#pragma unroll
  for (int m2 = 0; m2 < 16; ++m2) wsum += wr[m2];
  const float wn = (wsum > 0.f) ? (wr[n] / fmaxf(wsum, 1e-38f)) : 0.0625f;
  {
    uint32_t bb = bits;
    while (bb) {
      const int j = __builtin_ctz(bb);
      bb &= bb - 1u;
      atomicAdd(&wa[t + (j << 4)], wn);
    }
  }
  __syncthreads();

  // row sum + compact nonzeros
  float sp = wa[tid] + wa[tid + 256];
  for (int m = 1; m < 64; m <<= 1) sp += __shfl_xor(sp, m);
  if ((tid & 63) == 0) redc[tid >> 6] = sp;
  if (wa[tid] > 0.f)       { const int i = atomicAdd(&cnt, 1); list[i] = tid; }
  if (wa[tid + 256] > 0.f) { const int i = atomicAdd(&cnt, 1); list[i] = tid + 256; }
  __syncthreads();
  const float was = redc[0] + redc[1] + redc[2] + redc[3];
  const int nnz = cnt;

  // sparse attn @ V over ~16 nonzero k
  const int g = tid >> 6, d = tid & 63;
  const float* Vb = V + ((size_t)(b * 8 + h) * 512) * 64;
  float acc = 0.f;
  if (was > 0.f) {
    const float inv = 1.f / fmaxf(was, 1e-38f);
    for (int i = g; i < nnz; i += 4) {
      const int k = list[i];
      acc = fmaf(wa[k] * inv, Vb[(size_t)k * 64 + d], acc);
    }
  } else {
    for (int k = g; k < 512; k += 4) acc += Vb[(size_t)k * 64 + d];
    acc *= 0.001953125f;
  }
  psum[g][d] = acc;
  __syncthreads();
  if (g == 0) {
    ao[((size_t)(b * 512 + q) * 512) + h * 64 + d] =
        psum[0][d] + psum[1][d] + psum[2][d] + psum[3][d];
  }
}

// ---------------------------------------------------------------------------
extern "C" void kernel_launch(void* const* d_in, const int* in_sizes, int n_in,
                              void* d_out, int out_size, void* d_ws,
                              size_t ws_size, hipStream_t stream) {
  const float* x  = (const float*)d_in[0];
  const float* Wq = (const float*)d_in[1];
  const float* bq = (const float*)d_in[2];
  const float* Wk = (const float*)d_in[3];
  const float* bk = (const float*)d_in[4];
  const float* Wv = (const float*)d_in[5];
  const float* bv = (const float*)d_in[6];
  const float* Wo = (const float*)d_in[7];
  const float* bo = (const float*)d_in[8];
  float* out = (float*)d_out;

  float* ws = (float*)d_ws;
  float* Qw = ws;                  // 524288 f32  [B,H,S,dk]
  float* Kw = ws + 524288;         // 524288
  float* Vw = ws + 1048576;        // 524288
  float* tf = ws + 1572864;        // 4194304    [R=8192, 512]
  float* ao = ws + 5767168;        // 524288     [B,S,D]

  dim3 gq(16, 8, 3);
  qkv_gemm<<<gq, 256, 0, stream>>>(x, Wq, bq, Wk, bk, Wv, bv, Qw, Kw, Vw);
  scores_softmax<<<2048, 256, 0, stream>>>(Qw, Kw, tf);
  sample_attnv<<<8192, 256, 0, stream>>>(tf, Vw, ao);
  dim3 go(16, 8);
  out_gemm<<<go, 256, 0, stream>>>(ao, Wo, bo, out);
}

// Round 7
// 273.077 us; speedup vs baseline: 1.1637x; 1.1274x over previous
//
#include <hip/hip_runtime.h>
#include <cstdint>
#include <cstddef>

// B=2, S=512, D_MODEL=512, H=8, dk=64, N_SAMPLES=16; R = B*H*S = 8192 rows.
// JAX partitionable threefry: bits[i] = o0^o1, (o0,o1)=threefry2x32((0,42),(0,i))
// u = (float)(bits>>9) * 2^-23 ; select iff u < p ⟺ bits < (ceil(p*2^23))<<9

#if __has_builtin(__builtin_amdgcn_alignbit)
#define ROTL(x, r) __builtin_amdgcn_alignbit((x), (x), 32 - (r))
#else
#define ROTL(x, r) (((x) << (r)) | ((x) >> (32 - (r))))
#endif

// 4-wide interleaved threefry2x32, key (0,42): inputs are counters PRE-OFFSET
// by ks[1]=42; returns folded o0^o1 per chain.
__device__ __forceinline__ void tf4_fold(uint32_t ca, uint32_t cb, uint32_t cc,
                                         uint32_t cd, uint32_t &ra,
                                         uint32_t &rb, uint32_t &rc,
                                         uint32_t &rd) {
  uint32_t a0 = 0u, a1 = ca, b0 = 0u, b1 = cb;
  uint32_t c0 = 0u, c1 = cc, d0 = 0u, d1 = cd;
#define QR(s)                                                                 \
  a0 += a1; b0 += b1; c0 += c1; d0 += d1;                                     \
  a1 = ROTL(a1, s); b1 = ROTL(b1, s); c1 = ROTL(c1, s); d1 = ROTL(d1, s);     \
  a1 ^= a0; b1 ^= b0; c1 ^= c0; d1 ^= d0;
#define INJ(x, y)                                                             \
  a0 += (x); b0 += (x); c0 += (x); d0 += (x);                                 \
  a1 += (y); b1 += (y); c1 += (y); d1 += (y);
  QR(13) QR(15) QR(26) QR(6)
  INJ(42u, 0x1BD11BF1u)
  QR(17) QR(29) QR(16) QR(24)
  INJ(0x1BD11BF0u, 2u)
  QR(13) QR(15) QR(26) QR(6)
  a1 += 45u; b1 += 45u; c1 += 45u; d1 += 45u;   // x0 += ks[0]=0
  QR(17) QR(29) QR(16) QR(24)
  INJ(42u, 0x1BD11BF4u)
  QR(13) QR(15) QR(26) QR(6)
  INJ(0x1BD11BF0u, 5u)
#undef QR
#undef INJ
  ra = a0 ^ a1; rb = b0 ^ b1; rc = c0 ^ c1; rd = d0 ^ d1;
}

// ---------------------------------------------------------------------------
// Kernel A: QKV projection. grid=(16,8,3), block=256. 64x64 tile, BK=32.
// K (z==1) is stored TRANSPOSED: KT[bh][d][k] for coalesced score reads.
// k-accumulation order identical to prior rounds -> bit-exact Q/K/V.
// ---------------------------------------------------------------------------
__global__ __launch_bounds__(256)
void qkv_gemm(const float* __restrict__ x,
              const float* __restrict__ Wq, const float* __restrict__ bq,
              const float* __restrict__ Wk, const float* __restrict__ bk,
              const float* __restrict__ Wv, const float* __restrict__ bv,
              float* __restrict__ Qw, float* __restrict__ KTw,
              float* __restrict__ Vw) {
  const float* W; const float* bias; float* out;
  if (blockIdx.z == 0)      { W = Wq; bias = bq; out = Qw; }
  else if (blockIdx.z == 1) { W = Wk; bias = bk; out = KTw; }
  else                      { W = Wv; bias = bv; out = Vw; }

  __shared__ float At[32][68];   // [k][m]
  __shared__ float Bs[32][64];   // [k][n]
  const int tid = threadIdx.x;
  const int tx = tid & 15, ty = tid >> 4;
  const int row0 = blockIdx.x * 64, col0 = blockIdx.y * 64;
  float acc[4][4] = {};

  for (int kk = 0; kk < 512; kk += 32) {
    const int ar = tid >> 2;
#pragma unroll
    for (int i = 0; i < 2; ++i) {
      const int kc = ((tid & 3) << 3) + (i << 2);
      const float4 a4 =
          *(const float4*)&x[(size_t)(row0 + ar) * 512 + kk + kc];
      At[kc + 0][ar] = a4.x; At[kc + 1][ar] = a4.y;
      At[kc + 2][ar] = a4.z; At[kc + 3][ar] = a4.w;
    }
#pragma unroll
    for (int i = 0; i < 2; ++i) {
      const int idx = tid + (i << 8);
      const int br = idx >> 4, bc = (idx & 15) << 2;
      *(float4*)&Bs[br][bc] =
          *(const float4*)&W[(size_t)(kk + br) * 512 + col0 + bc];
    }
    __syncthreads();
#pragma unroll
    for (int p = 0; p < 32; ++p) {
      const float4 a4 = *(const float4*)&At[p][ty << 2];
      const float4 b4 = *(const float4*)&Bs[p][tx << 2];
      acc[0][0] = fmaf(a4.x, b4.x, acc[0][0]); acc[0][1] = fmaf(a4.x, b4.y, acc[0][1]);
      acc[0][2] = fmaf(a4.x, b4.z, acc[0][2]); acc[0][3] = fmaf(a4.x, b4.w, acc[0][3]);
      acc[1][0] = fmaf(a4.y, b4.x, acc[1][0]); acc[1][1] = fmaf(a4.y, b4.y, acc[1][1]);
      acc[1][2] = fmaf(a4.y, b4.z, acc[1][2]); acc[1][3] = fmaf(a4.y, b4.w, acc[1][3]);
      acc[2][0] = fmaf(a4.z, b4.x, acc[2][0]); acc[2][1] = fmaf(a4.z, b4.y, acc[2][1]);
      acc[2][2] = fmaf(a4.z, b4.z, acc[2][2]); acc[2][3] = fmaf(a4.z, b4.w, acc[2][3]);
      acc[3][0] = fmaf(a4.w, b4.x, acc[3][0]); acc[3][1] = fmaf(a4.w, b4.y, acc[3][1]);
      acc[3][2] = fmaf(a4.w, b4.z, acc[3][2]); acc[3][3] = fmaf(a4.w, b4.w, acc[3][3]);
    }
    __syncthreads();
  }
  const bool isK = (blockIdx.z == 1);
#pragma unroll
  for (int i = 0; i < 4; ++i) {
    const int row = row0 + (ty << 2) + i;
    const int b = row >> 9, s = row & 511;
#pragma unroll
    for (int j = 0; j < 4; ++j) {
      const int col = col0 + (tx << 2) + j;
      const int h = col >> 6, d = col & 63;
      const float v = acc[i][j] + bias[col];
      if (isK)
        out[(((size_t)(b * 8 + h) * 64 + d) * 512) + s] = v;   // KT[bh][d][k]
      else
        out[(((size_t)(b * 8 + h) * 512 + s) * 64) + d] = v;   // [bh][s][d]
    }
  }
}

// ---------------------------------------------------------------------------
// Kernel D: output projection. grid=(16,8). Same 64x64 structure.
// ---------------------------------------------------------------------------
__global__ __launch_bounds__(256)
void out_gemm(const float* __restrict__ A, const float* __restrict__ W,
              const float* __restrict__ bias, float* __restrict__ C) {
  __shared__ float At[32][68];
  __shared__ float Bs[32][64];
  const int tid = threadIdx.x;
  const int tx = tid & 15, ty = tid >> 4;
  const int row0 = blockIdx.x * 64, col0 = blockIdx.y * 64;
  float acc[4][4] = {};

  for (int kk = 0; kk < 512; kk += 32) {
    const int ar = tid >> 2;
#pragma unroll
    for (int i = 0; i < 2; ++i) {
      const int kc = ((tid & 3) << 3) + (i << 2);
      const float4 a4 =
          *(const float4*)&A[(size_t)(row0 + ar) * 512 + kk + kc];
      At[kc + 0][ar] = a4.x; At[kc + 1][ar] = a4.y;
      At[kc + 2][ar] = a4.z; At[kc + 3][ar] = a4.w;
    }
#pragma unroll
    for (int i = 0; i < 2; ++i) {
      const int idx = tid + (i << 8);
      const int br = idx >> 4, bc = (idx & 15) << 2;
      *(float4*)&Bs[br][bc] =
          *(const float4*)&W[(size_t)(kk + br) * 512 + col0 + bc];
    }
    __syncthreads();
#pragma unroll
    for (int p = 0; p < 32; ++p) {
      const float4 a4 = *(const float4*)&At[p][ty << 2];
      const float4 b4 = *(const float4*)&Bs[p][tx << 2];
      acc[0][0] = fmaf(a4.x, b4.x, acc[0][0]); acc[0][1] = fmaf(a4.x, b4.y, acc[0][1]);
      acc[0][2] = fmaf(a4.x, b4.z, acc[0][2]); acc[0][3] = fmaf(a4.x, b4.w, acc[0][3]);
      acc[1][0] = fmaf(a4.y, b4.x, acc[1][0]); acc[1][1] = fmaf(a4.y, b4.y, acc[1][1]);
      acc[1][2] = fmaf(a4.y, b4.z, acc[1][2]); acc[1][3] = fmaf(a4.y, b4.w, acc[1][3]);
      acc[2][0] = fmaf(a4.z, b4.x, acc[2][0]); acc[2][1] = fmaf(a4.z, b4.y, acc[2][1]);
      acc[2][2] = fmaf(a4.z, b4.z, acc[2][2]); acc[2][3] = fmaf(a4.z, b4.w, acc[2][3]);
      acc[3][0] = fmaf(a4.w, b4.x, acc[3][0]); acc[3][1] = fmaf(a4.w, b4.y, acc[3][1]);
      acc[3][2] = fmaf(a4.w, b4.z, acc[3][2]); acc[3][3] = fmaf(a4.w, b4.w, acc[3][3]);
    }
    __syncthreads();
  }
#pragma unroll
  for (int i = 0; i < 4; ++i) {
    const int row = row0 + (ty << 2) + i;
#pragma unroll
    for (int j = 0; j < 4; ++j) {
      const int col = col0 + (tx << 2) + j;
      C[(size_t)row * 512 + col] = acc[i][j] + bias[col];
    }
  }
}

// ---------------------------------------------------------------------------
// Kernel B: scores + softmax -> tf. 4 q-rows per block; K read from KT
// (coalesced across lanes: stride-512 rows, lane k consecutive).
// fmaf order over d identical to prior rounds -> tf bit-identical.
// ---------------------------------------------------------------------------
__global__ __launch_bounds__(256)
void scores_softmax(const float* __restrict__ Q, const float* __restrict__ KT,
                    float* __restrict__ tf_g) {
  const int blk = blockIdx.x;
  const int bh = blk >> 7, q0 = (blk & 127) << 2;
  const int tid = threadIdx.x;
  __shared__ __align__(16) float qs[4][64];
  __shared__ float redm[4][4], reds[4][4];
  qs[tid >> 6][tid & 63] =
      Q[((size_t)bh * 512 + q0 + (tid >> 6)) * 64 + (tid & 63)];
  __syncthreads();

  float sc[4][2];
#pragma unroll
  for (int ii = 0; ii < 2; ++ii) {
    const int k = tid + ii * 256;
    const float* Kp = KT + (size_t)bh * 64 * 512 + k;    // [d][k], stride 512
    float a0 = 0.f, a1 = 0.f, a2 = 0.f, a3 = 0.f;
#pragma unroll
    for (int d4 = 0; d4 < 16; ++d4) {
      const float4 v0 = ((const float4*)qs[0])[d4];
      const float4 v1 = ((const float4*)qs[1])[d4];
      const float4 v2 = ((const float4*)qs[2])[d4];
      const float4 v3 = ((const float4*)qs[3])[d4];
      const float k0 = Kp[(size_t)(d4 * 4 + 0) * 512];
      const float k1 = Kp[(size_t)(d4 * 4 + 1) * 512];
      const float k2 = Kp[(size_t)(d4 * 4 + 2) * 512];
      const float k3 = Kp[(size_t)(d4 * 4 + 3) * 512];
      a0 = fmaf(v0.x, k0, a0); a0 = fmaf(v0.y, k1, a0);
      a0 = fmaf(v0.z, k2, a0); a0 = fmaf(v0.w, k3, a0);
      a1 = fmaf(v1.x, k0, a1); a1 = fmaf(v1.y, k1, a1);
      a1 = fmaf(v1.z, k2, a1); a1 = fmaf(v1.w, k3, a1);
      a2 = fmaf(v2.x, k0, a2); a2 = fmaf(v2.y, k1, a2);
      a2 = fmaf(v2.z, k2, a2); a2 = fmaf(v2.w, k3, a2);
      a3 = fmaf(v3.x, k0, a3); a3 = fmaf(v3.y, k1, a3);
      a3 = fmaf(v3.z, k2, a3); a3 = fmaf(v3.w, k3, a3);
    }
    sc[0][ii] = a0 * 0.125f; sc[1][ii] = a1 * 0.125f;
    sc[2][ii] = a2 * 0.125f; sc[3][ii] = a3 * 0.125f;
  }
  float mx[4];
#pragma unroll
  for (int i = 0; i < 4; ++i) mx[i] = fmaxf(sc[i][0], sc[i][1]);
  for (int m = 1; m < 64; m <<= 1) {
#pragma unroll
    for (int i = 0; i < 4; ++i) mx[i] = fmaxf(mx[i], __shfl_xor(mx[i], m));
  }
  if ((tid & 63) == 0) {
    const int w = tid >> 6;
#pragma unroll
    for (int i = 0; i < 4; ++i) redm[i][w] = mx[i];
  }
  __syncthreads();
  float ex[4][2], sm[4];
#pragma unroll
  for (int i = 0; i < 4; ++i) {
    const float rm = fmaxf(fmaxf(redm[i][0], redm[i][1]),
                           fmaxf(redm[i][2], redm[i][3]));
    ex[i][0] = expf(sc[i][0] - rm);
    ex[i][1] = expf(sc[i][1] - rm);
    sm[i] = ex[i][0] + ex[i][1];
  }
  for (int m = 1; m < 64; m <<= 1) {
#pragma unroll
    for (int i = 0; i < 4; ++i) sm[i] += __shfl_xor(sm[i], m);
  }
  if ((tid & 63) == 0) {
    const int w = tid >> 6;
#pragma unroll
    for (int i = 0; i < 4; ++i) reds[i][w] = sm[i];
  }
  __syncthreads();
#pragma unroll
  for (int i = 0; i < 4; ++i) {
    const float tot = reds[i][0] + reds[i][1] + reds[i][2] + reds[i][3];
    tf_g[((size_t)bh * 512 + q0 + i) * 512 + tid]       = ex[i][0] / tot;
    tf_g[((size_t)bh * 512 + q0 + i) * 512 + tid + 256] = ex[i][1] / tot;
  }
}

// ---------------------------------------------------------------------------
// Kernel C: sampling + sparse weighted attn@V.  One block per row r.
// 16 samples x 16 lanes; lane t covers CONTIGUOUS k = t*32 + j, j<32, so the
// 32 thresholds load as 8 ds_read_b128 into registers -> pure-VALU hot loop.
// Per-element Bernoulli decisions bit-identical (same counter & threshold);
// only fp product grouping changes (~1e-7 on w, washes out in normalization).
// ---------------------------------------------------------------------------
__global__ __launch_bounds__(256)
void sample_attnv(const float* __restrict__ tf_g, const float* __restrict__ V,
                  float* __restrict__ ao) {
  const int r = blockIdx.x;                   // 0..8191
  const int b = r >> 12, h = (r >> 9) & 7, q = r & 511;
  const int tid = threadIdx.x;
  __shared__ float tf[512];
  __shared__ __align__(16) uint32_t pscu[512];   // ceil(p*2^23)<<9
  __shared__ float wa[512];
  __shared__ float wr[16];
  __shared__ float redc[8];
  __shared__ float psum[4][64];
  __shared__ int   list[512];
  __shared__ int   cnt;

  if (tid == 0) cnt = 0;
  {
    const float t0 = tf_g[(size_t)r * 512 + tid];
    const float t1 = tf_g[(size_t)r * 512 + tid + 256];
    tf[tid] = t0; tf[tid + 256] = t1;
    wa[tid] = 0.f; wa[tid + 256] = 0.f;
    const float p0 = fmaf(0.5f, t0, 0.0009765625f);
    const float p1 = fmaf(0.5f, t1, 0.0009765625f);
    pscu[tid]       = ((uint32_t)ceilf(p0 * 8388608.0f)) << 9;
    pscu[tid + 256] = ((uint32_t)ceilf(p1 * 8388608.0f)) << 9;
    float ql = (1.f - p0) * (1.f - p1);       // Qrow partial
    for (int m = 1; m < 64; m <<= 1) ql *= __shfl_xor(ql, m);
    if ((tid & 63) == 0) redc[4 + (tid >> 6)] = ql;
  }
  __syncthreads();
  const float Qrow = redc[4] * redc[5] * redc[6] * redc[7];

  const int n = tid >> 4, t = tid & 15;
  const int k0 = t << 5;                      // 32 contiguous k per lane
  uint4 pvv[8];
#pragma unroll
  for (int j = 0; j < 8; ++j) pvv[j] = *(const uint4*)&pscu[k0 + (j << 2)];

  const uint32_t cbase =
      (uint32_t)r * 8192u + (uint32_t)n * 512u + (uint32_t)k0 + 42u;
  uint32_t bits = 0u;
#pragma unroll
  for (int j = 0; j < 32; j += 4) {
    uint32_t ra, rb, rc, rd;
    tf4_fold(cbase + (uint32_t)j, cbase + (uint32_t)j + 1u,
             cbase + (uint32_t)j + 2u, cbase + (uint32_t)j + 3u,
             ra, rb, rc, rd);
    const uint4 p4 = pvv[j >> 2];
    bits |= (ra < p4.x ? 1u : 0u) << j;
    bits |= (rb < p4.y ? 1u : 0u) << (j + 1);
    bits |= (rc < p4.z ? 1u : 0u) << (j + 2);
    bits |= (rd < p4.w ? 1u : 0u) << (j + 3);
  }

  // rare path: selected-term products (expected ~1 selection per sample)
  float ptl = 1.f, ratl = 1.f;
  int cl = __popc(bits);
  {
    uint32_t bb = bits;
    while (bb) {
      const int j = __builtin_ctz(bb);
      bb &= bb - 1u;
      const float tv = tf[k0 + j];
      const float p = fmaf(0.5f, tv, 0.0009765625f);
      ptl *= tv;
      ratl *= p / (1.f - p);
    }
  }
#pragma unroll
  for (int m = 1; m < 16; m <<= 1) {
    ptl *= __shfl_xor(ptl, m);
    ratl *= __shfl_xor(ratl, m);
    cl += __shfl_xor(cl, m);
  }
  if (t == 0) {
    const float pp = Qrow * ratl;
    wr[n] = (cl > 0 && pp > 0.f) ? (ptl / fmaxf(pp, 1e-38f)) : 0.f;
  }
  __syncthreads();
  float wsum = 0.f;
#pragma unroll
  for (int m2 = 0; m2 < 16; ++m2) wsum += wr[m2];
  const float wn = (wsum > 0.f) ? (wr[n] / fmaxf(wsum, 1e-38f)) : 0.0625f;
  {
    uint32_t bb = bits;
    while (bb) {
      const int j = __builtin_ctz(bb);
      bb &= bb - 1u;
      atomicAdd(&wa[k0 + j], wn);
    }
  }
  __syncthreads();

  // row sum + compact nonzeros
  float sp = wa[tid] + wa[tid + 256];
  for (int m = 1; m < 64; m <<= 1) sp += __shfl_xor(sp, m);
  if ((tid & 63) == 0) redc[tid >> 6] = sp;
  if (wa[tid] > 0.f)       { const int i = atomicAdd(&cnt, 1); list[i] = tid; }
  if (wa[tid + 256] > 0.f) { const int i = atomicAdd(&cnt, 1); list[i] = tid + 256; }
  __syncthreads();
  const float was = redc[0] + redc[1] + redc[2] + redc[3];
  const int nnz = cnt;

  // sparse attn @ V over ~16 nonzero k
  const int g = tid >> 6, d = tid & 63;
  const float* Vb = V + ((size_t)(b * 8 + h) * 512) * 64;
  float acc = 0.f;
  if (was > 0.f) {
    const float inv = 1.f / fmaxf(was, 1e-38f);
    for (int i = g; i < nnz; i += 4) {
      const int k = list[i];
      acc = fmaf(wa[k] * inv, Vb[(size_t)k * 64 + d], acc);
    }
  } else {
    for (int k = g; k < 512; k += 4) acc += Vb[(size_t)k * 64 + d];
    acc *= 0.001953125f;
  }
  psum[g][d] = acc;
  __syncthreads();
  if (g == 0) {
    ao[((size_t)(b * 512 + q) * 512) + h * 64 + d] =
        psum[0][d] + psum[1][d] + psum[2][d] + psum[3][d];
  }
}

// ---------------------------------------------------------------------------
extern "C" void kernel_launch(void* const* d_in, const int* in_sizes, int n_in,
                              void* d_out, int out_size, void* d_ws,
                              size_t ws_size, hipStream_t stream) {
  const float* x  = (const float*)d_in[0];
  const float* Wq = (const float*)d_in[1];
  const float* bq = (const float*)d_in[2];
  const float* Wk = (const float*)d_in[3];
  const float* bk = (const float*)d_in[4];
  const float* Wv = (const float*)d_in[5];
  const float* bv = (const float*)d_in[6];
  const float* Wo = (const float*)d_in[7];
  const float* bo = (const float*)d_in[8];
  float* out = (float*)d_out;

  float* ws = (float*)d_ws;
  float* Qw = ws;                  // 524288 f32  [B,H,S,dk]
  float* KT = ws + 524288;         // 524288     [B,H,dk,S]  (transposed K)
  float* Vw = ws + 1048576;        // 524288
  float* tf = ws + 1572864;        // 4194304    [R=8192, 512]
  float* ao = ws + 5767168;        // 524288     [B,S,D]

  dim3 gq(16, 8, 3);
  qkv_gemm<<<gq, 256, 0, stream>>>(x, Wq, bq, Wk, bk, Wv, bv, Qw, KT, Vw);
  scores_softmax<<<2048, 256, 0, stream>>>(Qw, KT, tf);
  sample_attnv<<<8192, 256, 0, stream>>>(tf, Vw, ao);
  dim3 go(16, 8);
  out_gemm<<<go, 256, 0, stream>>>(ao, Wo, bo, out);
}